// Round 4
// baseline (113.065 us; speedup 1.0000x reference)
//
#include <hip/hip_runtime.h>
#include <math.h>

// Problem constants (fixed by the reference)
constexpr int Bc = 4096;
constexpr int Tc = 200;
constexpr int Cc = 38;   // classes (0 = blank)
constexpr int Sc = 30;   // max target length
constexpr int Lc = 2 * Sc + 1;  // 61 lattice states
constexpr int CH = 64;   // chunk rows staged in LDS
constexpr int RPF = 38;  // row floats in LDS (152 B, 8B-aligned rows)
#define NEGV (-1e9f)
#define LOG2E 1.4426950408889634f
#define LN2   0.6931471805599453f

// DPP wave_shr:1 — lane i gets v from lane i-1, lane 0 keeps `fill`.
__device__ __forceinline__ float dpp_shr1(float v, float fill) {
    int r = __builtin_amdgcn_update_dpp(__float_as_int(fill), __float_as_int(v),
                                        0x138, 0xF, 0xF, false);
    return __int_as_float(r);
}

__device__ __forceinline__ void lds_fence() {
    // wave-local LDS handoff: lanes run in lockstep, so lgkmcnt(0) makes all
    // the wave's ds_writes visible to its own ds_reads. sched_barrier per rule #18.
    asm volatile("s_waitcnt lgkmcnt(0)" ::: "memory");
    __builtin_amdgcn_sched_barrier(0);
}

// One wave (64 lanes) per sample; 4 waves (4 samples) per block.
__global__ __launch_bounds__(256) void ctc_fused_kernel(
    const float* __restrict__ input,   // [B,T,C]
    const int*   __restrict__ target,  // [B,S]
    const int*   __restrict__ ilen,    // [B]
    const int*   __restrict__ tlen,    // [B]
    const int*   __restrict__ pos,     // [B,S]
    const float* __restrict__ ms,      // [37,37,37]
    float*       __restrict__ contrib) // [B]
{
    __shared__ float lds_rows[4][CH * RPF];   // 38912 B -> 4 blocks/CU
    const int lane = threadIdx.x & 63;
    const int wv = threadIdx.x >> 6;
    const int b = blockIdx.x * 4 + wv;
    if (b >= Bc) return;                      // no block-wide barriers used
    float* mylds = lds_rows[wv];

    // ---- lattice statics: lane l = lattice state l ----
    int ext = 0; bool skip = false;
    if (lane < Lc && (lane & 1)) {
        int s = (lane - 1) >> 1;
        ext = target[b * Sc + s];                        // 1..37
        int prev = (s > 0) ? target[b * Sc + s - 1] : 0;
        skip = (ext != prev);
    }
    const float* row = input + (size_t)b * Tc * Cc;
    const int il = ilen[b];
    const int tl = tlen[b];

    float2 S[19], S2[19];                 // reg-staged rows (ping-pong)
    float cl = 0.0f;                      // per-lane partial sum of lse (t < il)
    float beta = (lane == 0) ? 0.0f : NEGV;  // log2-shifted alpha

    // prologue: load chunk 0 (rows 0..63, all valid)
    {
        const float2* p = (const float2*)(row + (size_t)lane * Cc);
        #pragma unroll
        for (int j = 0; j < 19; ++j) S[j] = p[j];
    }

    // ---- chunks 0..2 (full, 64 rows each) ----
    for (int c = 0; c < 3; ++c) {
        const int cbase = c * CH;
        lds_fence();  // WAR: previous chunk's ds_reads retired before overwrite
        // stage my row -> LDS (19x ds_write_b64, rows 8B-aligned at l*152)
        {
            float2* q = (float2*)(mylds + lane * RPF);
            #pragma unroll
            for (int j = 0; j < 19; ++j) q[j] = S[j];
        }
        // T14 issue-early: next chunk's global loads into S2 (waited at loop end by compiler)
        {
            const int nb_ = cbase + CH;
            const int nrows = (Tc - nb_ < CH) ? (Tc - nb_) : CH;  // 64,64,8
            const float2* p = (const float2*)(row + ((size_t)nb_ + lane) * Cc);
            bool v = lane < nrows;
            #pragma unroll
            for (int j = 0; j < 19; ++j) S2[j] = v ? p[j] : make_float2(0.f, 0.f);
        }
        // lse of my row from regs (overlaps ds_write drain)
        {
            float m = fmaxf(S[0].x, S[0].y);
            #pragma unroll
            for (int j = 1; j < 19; ++j) m = fmaxf(m, fmaxf(S[j].x, S[j].y));
            float se = 0.f;
            #pragma unroll
            for (int j = 0; j < 19; ++j) se += __expf(S[j].x - m) + __expf(S[j].y - m);
            if (cbase + lane < il) cl += m + __logf(se);
        }
        lds_fence();  // RAW: ds_writes visible to cross-lane ds_reads
        // emission gather (batched ds_read_b32) + serial recursion
        float e[CH];
        #pragma unroll
        for (int k = 0; k < CH; ++k) e[k] = mylds[k * RPF + ext];
        #pragma unroll
        for (int k = 0; k < CH; ++k) {
            float e2 = e[k] * LOG2E;
            float b1 = dpp_shr1(beta, NEGV);
            float b2 = dpp_shr1(b1, NEGV);
            b2 = skip ? b2 : NEGV;
            float m3 = fmaxf(fmaxf(beta, b1), b2);
            float s3 = exp2f(beta - m3) + exp2f(b1 - m3) + exp2f(b2 - m3);
            float nbv = m3 + __log2f(s3) + e2;
            beta = (cbase + k < il) ? nbv : beta;
        }
        #pragma unroll
        for (int j = 0; j < 19; ++j) S[j] = S2[j];   // ping-pong copy (static idx)
    }

    // ---- last chunk: 8 rows (t = 192..199) ----
    {
        const int cbase = 3 * CH;
        const int nrows = Tc - cbase;   // 8
        lds_fence();
        if (lane < nrows) {
            float2* q = (float2*)(mylds + lane * RPF);
            #pragma unroll
            for (int j = 0; j < 19; ++j) q[j] = S[j];
            float m = fmaxf(S[0].x, S[0].y);
            #pragma unroll
            for (int j = 1; j < 19; ++j) m = fmaxf(m, fmaxf(S[j].x, S[j].y));
            float se = 0.f;
            #pragma unroll
            for (int j = 0; j < 19; ++j) se += __expf(S[j].x - m) + __expf(S[j].y - m);
            if (cbase + lane < il) cl += m + __logf(se);
        }
        lds_fence();
        float e[8];
        #pragma unroll
        for (int k = 0; k < 8; ++k) e[k] = mylds[k * RPF + ext];
        #pragma unroll
        for (int k = 0; k < 8; ++k) {
            float e2 = e[k] * LOG2E;
            float b1 = dpp_shr1(beta, NEGV);
            float b2 = dpp_shr1(b1, NEGV);
            b2 = skip ? b2 : NEGV;
            float m3 = fmaxf(fmaxf(beta, b1), b2);
            float s3 = exp2f(beta - m3) + exp2f(b1 - m3) + exp2f(b2 - m3);
            float nbv = m3 + __log2f(s3) + e2;
            beta = (cbase + k < il) ? nbv : beta;
        }
    }

    // ---- KL tail: preload all rows/ms values (latency overlapped), then reduce ----
    int posv = 0, tgv = 0;
    if (lane < Sc) {
        posv = pos[b * Sc + lane];
        tgv  = target[b * Sc + lane];
    }
    float xs[Sc], msv[Sc];
    #pragma unroll
    for (int s = 0; s < Sc; ++s) {
        int ps = __shfl(posv, s);
        int tg = __shfl(tgv, s);
        int f  = (s > 0) ? __shfl(tgv, s - 1) : (Cc - 1);
        bool live = (s < tl);
        xs[s]  = (live && lane < Cc) ? row[(size_t)ps * Cc + lane] : 0.0f;
        msv[s] = (live && lane >= 1 && lane < Cc)
                   ? ms[((size_t)(f - 1) * 37 + (tg - 1)) * 37 + (lane - 1)] : 0.0f;
    }
    float klacc = 0.0f;
    #pragma unroll
    for (int s = 0; s < Sc; ++s) {
        if (s < tl) {
            float x = (lane < Cc) ? xs[s] : -1e30f;
            float m = x;
            #pragma unroll
            for (int o = 32; o; o >>= 1) m = fmaxf(m, __shfl_xor(m, o));
            float se = (lane < Cc) ? __expf(x - m) : 0.0f;
            #pragma unroll
            for (int o = 32; o; o >>= 1) se += __shfl_xor(se, o);
            float lsr = m + __logf(se);
            float tv = (lane == 0) ? 1e-10f : ((lane < Cc) ? msv[s] + 1e-10f : 0.0f);
            float term = (lane < Cc) ? tv * (__logf(tv) - (x - lsr)) : 0.0f;
            #pragma unroll
            for (int o = 32; o; o >>= 1) term += __shfl_xor(term, o);
            klacc += term;
        }
    }

    // ---- epilogue ----
    #pragma unroll
    for (int o = 32; o; o >>= 1) cl += __shfl_xor(cl, o);

    const int idx = 2 * tl;                 // 10..60
    float last  = __shfl(beta, idx);
    float last2 = __shfl(beta, idx - 1);
    float mx = fmaxf(last, last2);
    float l2 = (mx + __log2f(exp2f(last - mx) + exp2f(last2 - mx))) * LN2;
    float nll = cl - l2;
    if (nll > 1e8f) nll = 0.0f;             // zero_infinity
    float Lf = (float)tl;
    float ctc_part = nll / (Lf * (float)Bc);
    float smoothing = 1.0f - __expf(-0.05129329438755058f / Lf);  // 1 - 0.95^(1/Lf)
    float kld = klacc * smoothing / ((float)Cc * Lf);

    if (lane == 0) contrib[b] = ctc_part + kld;
}

// Deterministic single-block tree reduction of B floats -> out[0]
__global__ __launch_bounds__(256) void reduce_kernel(
    const float* __restrict__ in, float* __restrict__ out, int n)
{
    __shared__ float sdata[256];
    float s = 0.0f;
    for (int i = threadIdx.x; i < n; i += 256) s += in[i];
    sdata[threadIdx.x] = s;
    __syncthreads();
    for (int off = 128; off; off >>= 1) {
        if ((int)threadIdx.x < off) sdata[threadIdx.x] += sdata[threadIdx.x + off];
        __syncthreads();
    }
    if (threadIdx.x == 0) out[0] = sdata[0];
}

extern "C" void kernel_launch(void* const* d_in, const int* in_sizes, int n_in,
                              void* d_out, int out_size, void* d_ws, size_t ws_size,
                              hipStream_t stream) {
    const float* input  = (const float*)d_in[0];
    const int*   target = (const int*)d_in[1];
    const int*   ilen   = (const int*)d_in[2];
    const int*   tlen   = (const int*)d_in[3];
    const int*   pos    = (const int*)d_in[4];
    const float* ms     = (const float*)d_in[5];
    float* out = (float*)d_out;
    float* contrib = (float*)d_ws;  // B floats

    ctc_fused_kernel<<<Bc / 4, 256, 0, stream>>>(input, target, ilen, tlen, pos, ms, contrib);
    reduce_kernel<<<1, 256, 0, stream>>>(contrib, out, Bc);
}

// Round 5
// 112.768 us; speedup vs baseline: 1.0026x; 1.0026x over previous
//
#include <hip/hip_runtime.h>
#include <math.h>

// Problem constants (fixed by the reference)
constexpr int Bc = 4096;
constexpr int Tc = 200;
constexpr int Cc = 38;   // classes (0 = blank)
constexpr int Sc = 30;   // max target length
constexpr int Lc = 2 * Sc + 1;  // 61 lattice states
constexpr int CH = 64;   // chunk rows staged in LDS
constexpr int RPF = 38;  // row floats in LDS (152 B, 8B-aligned rows)
#define NEGV (-1e9f)
#define LOG2E 1.4426950408889634f
#define LN2   0.6931471805599453f

// DPP wave_shr:1 — lane i gets v from lane i-1, lane 0 keeps `fill`.
__device__ __forceinline__ float dpp_shr1(float v, float fill) {
    int r = __builtin_amdgcn_update_dpp(__float_as_int(fill), __float_as_int(v),
                                        0x138, 0xF, 0xF, false);
    return __int_as_float(r);
}

__device__ __forceinline__ void lds_fence() {
    // wave-local LDS handoff: lanes run in lockstep, so lgkmcnt(0) makes all
    // the wave's ds_writes visible to its own ds_reads. sched_barrier per rule #18.
    asm volatile("s_waitcnt lgkmcnt(0)" ::: "memory");
    __builtin_amdgcn_sched_barrier(0);
}

// One wave (64 lanes) per sample; 4 waves (4 samples) per block.
__global__ __launch_bounds__(256) void ctc_fused_kernel(
    const float* __restrict__ input,   // [B,T,C]
    const int*   __restrict__ target,  // [B,S]
    const int*   __restrict__ ilen,    // [B]
    const int*   __restrict__ tlen,    // [B]
    const int*   __restrict__ pos,     // [B,S]
    const float* __restrict__ ms,      // [37,37,37]
    float*       __restrict__ contrib) // [B]
{
    __shared__ float lds_rows[4][CH * RPF];   // 38912 B -> 4 blocks/CU
    const int lane = threadIdx.x & 63;
    const int wv = threadIdx.x >> 6;
    const int b = blockIdx.x * 4 + wv;
    if (b >= Bc) return;                      // no block-wide barriers used
    float* mylds = lds_rows[wv];

    // ---- lattice statics: lane l = lattice state l ----
    int ext = 0; bool skip = false;
    if (lane < Lc && (lane & 1)) {
        int s = (lane - 1) >> 1;
        ext = target[b * Sc + s];                        // 1..37
        int prev = (s > 0) ? target[b * Sc + s - 1] : 0;
        skip = (ext != prev);
    }
    const float* row = input + (size_t)b * Tc * Cc;
    const int il = ilen[b];
    const int tl = tlen[b];

    float2 S[19], S2[19];                 // reg-staged rows (ping-pong)
    float cl = 0.0f;                      // per-lane partial sum of lse (t < il)
    float beta = (lane == 0) ? 0.0f : NEGV;  // log2-shifted alpha

    // prologue: load chunk 0 (rows 0..63, all valid)
    {
        const float2* p = (const float2*)(row + (size_t)lane * Cc);
        #pragma unroll
        for (int j = 0; j < 19; ++j) S[j] = p[j];
    }

    // ---- chunks 0..2 (full, 64 rows each) ----
    for (int c = 0; c < 3; ++c) {
        const int cbase = c * CH;
        lds_fence();  // WAR: previous chunk's ds_reads retired before overwrite
        // stage my row -> LDS (19x ds_write_b64, rows 8B-aligned at l*152)
        {
            float2* q = (float2*)(mylds + lane * RPF);
            #pragma unroll
            for (int j = 0; j < 19; ++j) q[j] = S[j];
        }
        // T14 issue-early: next chunk's global loads into S2 (waited at loop end by compiler)
        {
            const int nb_ = cbase + CH;
            const int nrows = (Tc - nb_ < CH) ? (Tc - nb_) : CH;  // 64,64,8
            const float2* p = (const float2*)(row + ((size_t)nb_ + lane) * Cc);
            bool v = lane < nrows;
            #pragma unroll
            for (int j = 0; j < 19; ++j) S2[j] = v ? p[j] : make_float2(0.f, 0.f);
        }
        // lse of my row from regs (overlaps ds_write drain)
        {
            float m = fmaxf(S[0].x, S[0].y);
            #pragma unroll
            for (int j = 1; j < 19; ++j) m = fmaxf(m, fmaxf(S[j].x, S[j].y));
            float se = 0.f;
            #pragma unroll
            for (int j = 0; j < 19; ++j) se += __expf(S[j].x - m) + __expf(S[j].y - m);
            if (cbase + lane < il) cl += m + __logf(se);
        }
        lds_fence();  // RAW: ds_writes visible to cross-lane ds_reads
        // emission gather (batched ds_read_b32) + serial recursion
        float e[CH];
        #pragma unroll
        for (int k = 0; k < CH; ++k) e[k] = mylds[k * RPF + ext];
        #pragma unroll
        for (int k = 0; k < CH; ++k) {
            float e2 = e[k] * LOG2E;
            float b1 = dpp_shr1(beta, NEGV);
            float b2 = dpp_shr1(b1, NEGV);
            b2 = skip ? b2 : NEGV;
            float m3 = fmaxf(fmaxf(beta, b1), b2);
            float s3 = exp2f(beta - m3) + exp2f(b1 - m3) + exp2f(b2 - m3);
            float nbv = m3 + __log2f(s3) + e2;
            beta = (cbase + k < il) ? nbv : beta;
        }
        #pragma unroll
        for (int j = 0; j < 19; ++j) S[j] = S2[j];   // ping-pong copy (static idx)
    }

    // ---- last chunk: 8 rows (t = 192..199) ----
    {
        const int cbase = 3 * CH;
        const int nrows = Tc - cbase;   // 8
        lds_fence();
        if (lane < nrows) {
            float2* q = (float2*)(mylds + lane * RPF);
            #pragma unroll
            for (int j = 0; j < 19; ++j) q[j] = S[j];
            float m = fmaxf(S[0].x, S[0].y);
            #pragma unroll
            for (int j = 1; j < 19; ++j) m = fmaxf(m, fmaxf(S[j].x, S[j].y));
            float se = 0.f;
            #pragma unroll
            for (int j = 0; j < 19; ++j) se += __expf(S[j].x - m) + __expf(S[j].y - m);
            if (cbase + lane < il) cl += m + __logf(se);
        }
        lds_fence();
        float e[8];
        #pragma unroll
        for (int k = 0; k < 8; ++k) e[k] = mylds[k * RPF + ext];
        #pragma unroll
        for (int k = 0; k < 8; ++k) {
            float e2 = e[k] * LOG2E;
            float b1 = dpp_shr1(beta, NEGV);
            float b2 = dpp_shr1(b1, NEGV);
            b2 = skip ? b2 : NEGV;
            float m3 = fmaxf(fmaxf(beta, b1), b2);
            float s3 = exp2f(beta - m3) + exp2f(b1 - m3) + exp2f(b2 - m3);
            float nbv = m3 + __log2f(s3) + e2;
            beta = (cbase + k < il) ? nbv : beta;
        }
    }

    // ---- KL tail: preload all rows/ms values (latency overlapped), then reduce ----
    int posv = 0, tgv = 0;
    if (lane < Sc) {
        posv = pos[b * Sc + lane];
        tgv  = target[b * Sc + lane];
    }
    float xs[Sc], msv[Sc];
    #pragma unroll
    for (int s = 0; s < Sc; ++s) {
        int ps = __shfl(posv, s);
        int tg = __shfl(tgv, s);
        int f  = (s > 0) ? __shfl(tgv, s - 1) : (Cc - 1);
        bool live = (s < tl);
        xs[s]  = (live && lane < Cc) ? row[(size_t)ps * Cc + lane] : 0.0f;
        msv[s] = (live && lane >= 1 && lane < Cc)
                   ? ms[((size_t)(f - 1) * 37 + (tg - 1)) * 37 + (lane - 1)] : 0.0f;
    }
    float klacc = 0.0f;
    #pragma unroll
    for (int s = 0; s < Sc; ++s) {
        if (s < tl) {
            float x = (lane < Cc) ? xs[s] : -1e30f;
            float m = x;
            #pragma unroll
            for (int o = 32; o; o >>= 1) m = fmaxf(m, __shfl_xor(m, o));
            float se = (lane < Cc) ? __expf(x - m) : 0.0f;
            #pragma unroll
            for (int o = 32; o; o >>= 1) se += __shfl_xor(se, o);
            float lsr = m + __logf(se);
            float tv = (lane == 0) ? 1e-10f : ((lane < Cc) ? msv[s] + 1e-10f : 0.0f);
            float term = (lane < Cc) ? tv * (__logf(tv) - (x - lsr)) : 0.0f;
            #pragma unroll
            for (int o = 32; o; o >>= 1) term += __shfl_xor(term, o);
            klacc += term;
        }
    }

    // ---- epilogue ----
    #pragma unroll
    for (int o = 32; o; o >>= 1) cl += __shfl_xor(cl, o);

    const int idx = 2 * tl;                 // 10..60
    float last  = __shfl(beta, idx);
    float last2 = __shfl(beta, idx - 1);
    float mx = fmaxf(last, last2);
    float l2 = (mx + __log2f(exp2f(last - mx) + exp2f(last2 - mx))) * LN2;
    float nll = cl - l2;
    if (nll > 1e8f) nll = 0.0f;             // zero_infinity
    float Lf = (float)tl;
    float ctc_part = nll / (Lf * (float)Bc);
    float smoothing = 1.0f - __expf(-0.05129329438755058f / Lf);  // 1 - 0.95^(1/Lf)
    float kld = klacc * smoothing / ((float)Cc * Lf);

    if (lane == 0) contrib[b] = ctc_part + kld;
}

// Deterministic single-block tree reduction of B floats -> out[0]
__global__ __launch_bounds__(256) void reduce_kernel(
    const float* __restrict__ in, float* __restrict__ out, int n)
{
    __shared__ float sdata[256];
    float s = 0.0f;
    for (int i = threadIdx.x; i < n; i += 256) s += in[i];
    sdata[threadIdx.x] = s;
    __syncthreads();
    for (int off = 128; off; off >>= 1) {
        if ((int)threadIdx.x < off) sdata[threadIdx.x] += sdata[threadIdx.x + off];
        __syncthreads();
    }
    if (threadIdx.x == 0) out[0] = sdata[0];
}

extern "C" void kernel_launch(void* const* d_in, const int* in_sizes, int n_in,
                              void* d_out, int out_size, void* d_ws, size_t ws_size,
                              hipStream_t stream) {
    const float* input  = (const float*)d_in[0];
    const int*   target = (const int*)d_in[1];
    const int*   ilen   = (const int*)d_in[2];
    const int*   tlen   = (const int*)d_in[3];
    const int*   pos    = (const int*)d_in[4];
    const float* ms     = (const float*)d_in[5];
    float* out = (float*)d_out;
    float* contrib = (float*)d_ws;  // B floats

    ctc_fused_kernel<<<Bc / 4, 256, 0, stream>>>(input, target, ilen, tlen, pos, ms, contrib);
    reduce_kernel<<<1, 256, 0, stream>>>(contrib, out, Bc);
}

// Round 6
// 110.770 us; speedup vs baseline: 1.0207x; 1.0180x over previous
//
#include <hip/hip_runtime.h>
#include <math.h>

// Problem constants (fixed by the reference)
constexpr int Bc = 4096;
constexpr int Tc = 200;
constexpr int Cc = 38;   // classes (0 = blank)
constexpr int Sc = 30;   // max target length
constexpr int Lc = 2 * Sc + 1;  // 61 lattice states
constexpr int CH = 32;   // rows per staged chunk
constexpr int RPF = 38;  // floats per row (152 B)
constexpr int CHB = CH * RPF * 4;  // 4864 bytes per chunk
constexpr int NFULL = 6;           // 6*32 = 192 rows; tail = 8 rows
#define NEGV (-1e9f)
#define LOG2E 1.4426950408889634f
#define LN2   0.6931471805599453f

typedef const __attribute__((address_space(1))) void* gas_t;
typedef __attribute__((address_space(3))) void* las_t;

// DPP wave_shr:1 — lane i gets v from lane i-1, lane 0 keeps `fill`.
__device__ __forceinline__ float dpp_shr1(float v, float fill) {
    int r = __builtin_amdgcn_update_dpp(__float_as_int(fill), __float_as_int(v),
                                        0x138, 0xF, 0xF, false);
    return __int_as_float(r);
}

// Stage one contiguous 4864-B chunk HBM -> LDS with zero VGPR staging.
// 4 x (64 lanes x 16B) + 3 x (64 lanes x 4B) = 7 VMEM issues, counted in vmcnt.
__device__ __forceinline__ void stage_chunk(const char* g, float* l, int lane) {
    char* lb = (char*)l;
    #pragma unroll
    for (int i = 0; i < 4; ++i)
        __builtin_amdgcn_global_load_lds((gas_t)(g + i * 1024 + lane * 16),
                                         (las_t)(lb + i * 1024), 16, 0, 0);
    #pragma unroll
    for (int i = 0; i < 3; ++i)
        __builtin_amdgcn_global_load_lds((gas_t)(g + 4096 + i * 256 + lane * 4),
                                         (las_t)(lb + 4096 + i * 256), 4, 0, 0);
}

// One wave (64 lanes) per sample; 4 waves per block; 4 blocks/CU -> all resident.
__global__ __launch_bounds__(256, 4) void ctc_fused_kernel(
    const float* __restrict__ input,   // [B,T,C]
    const int*   __restrict__ target,  // [B,S]
    const int*   __restrict__ ilen,    // [B]
    const int*   __restrict__ tlen,    // [B]
    const int*   __restrict__ pos,     // [B,S]
    const float* __restrict__ ms,      // [37,37,37]
    float*       __restrict__ contrib) // [B]
{
    __shared__ __align__(16) float lds_rows[4][2 * CH * RPF];  // 38912 B/block
    const int lane = threadIdx.x & 63;
    const int wv = threadIdx.x >> 6;
    const int b = blockIdx.x * 4 + wv;
    float* buf0 = lds_rows[wv];
    float* buf1 = buf0 + CH * RPF;

    // ---- lattice statics: lane l = lattice state l ----
    int ext = 0; bool skip = false;
    if (lane < Lc && (lane & 1)) {
        int s = (lane - 1) >> 1;
        ext = target[b * Sc + s];                        // 1..37
        int prev = (s > 0) ? target[b * Sc + s - 1] : 0;
        skip = (ext != prev);
    }
    const float* row = input + (size_t)b * Tc * Cc;
    const char* gin = (const char*)row;
    const int il = ilen[b];
    const int tl = tlen[b];

    // prologue: two chunks in flight
    stage_chunk(gin + 0 * CHB, buf0, lane);
    stage_chunk(gin + 1 * CHB, buf1, lane);

    float cl = 0.0f;                          // per-lane partial sum of lse (t < il)
    float beta = (lane == 0) ? 0.0f : NEGV;   // log2-shifted alpha

    for (int c = 0; c < NFULL; ++c) {
        float* cur = (c & 1) ? buf1 : buf0;
        // counted wait: chunk c landed; chunk c+1's 7 issues stay in flight
        if (c < NFULL - 1) { asm volatile("s_waitcnt vmcnt(7)" ::: "memory"); }
        else               { asm volatile("s_waitcnt vmcnt(0)" ::: "memory"); }
        __builtin_amdgcn_sched_barrier(0);
        const int t0 = c * CH;

        // per-row lse from LDS (lanes 0..31, one row each; 2-way bank = free)
        if (lane < CH) {
            const float2* pr = (const float2*)(cur + lane * RPF);
            float2 r[19];
            #pragma unroll
            for (int j = 0; j < 19; ++j) r[j] = pr[j];
            float m = fmaxf(r[0].x, r[0].y);
            #pragma unroll
            for (int j = 1; j < 19; ++j) m = fmaxf(m, fmaxf(r[j].x, r[j].y));
            float se = 0.f;
            #pragma unroll
            for (int j = 0; j < 19; ++j) se += __expf(r[j].x - m) + __expf(r[j].y - m);
            if (t0 + lane < il) cl += m + __logf(se);
        }

        // emission gather (batched ds_read) + serial recursion
        float e[CH];
        #pragma unroll
        for (int k = 0; k < CH; ++k) e[k] = cur[k * RPF + ext];
        #pragma unroll
        for (int k = 0; k < CH; ++k) {
            float e2 = e[k] * LOG2E;
            float b1 = dpp_shr1(beta, NEGV);
            float b2 = dpp_shr1(b1, NEGV);
            b2 = skip ? b2 : NEGV;
            float m3 = fmaxf(fmaxf(beta, b1), b2);
            float s3 = exp2f(beta - m3) + exp2f(b1 - m3) + exp2f(b2 - m3);
            float nbv = m3 + __log2f(s3) + e2;
            beta = (t0 + k < il) ? nbv : beta;
        }

        // re-stage this buffer with chunk c+2 (WAR: all our LDS reads retired first)
        if (c + 2 < NFULL) {
            asm volatile("s_waitcnt lgkmcnt(0)" ::: "memory");
            __builtin_amdgcn_sched_barrier(0);
            stage_chunk(gin + (c + 2) * CHB, cur, lane);
        }
    }

    // ---- tail: rows 192..199 via reg staging into buf0 ----
    {
        asm volatile("s_waitcnt lgkmcnt(0)" ::: "memory");
        __builtin_amdgcn_sched_barrier(0);
        const int t0 = NFULL * CH;             // 192
        if (lane < Tc - t0) {                  // 8 rows
            const float2* p = (const float2*)(row + (size_t)(t0 + lane) * Cc);
            float2 r[19];
            #pragma unroll
            for (int j = 0; j < 19; ++j) r[j] = p[j];
            float2* q = (float2*)(buf0 + lane * RPF);
            #pragma unroll
            for (int j = 0; j < 19; ++j) q[j] = r[j];
            float m = fmaxf(r[0].x, r[0].y);
            #pragma unroll
            for (int j = 1; j < 19; ++j) m = fmaxf(m, fmaxf(r[j].x, r[j].y));
            float se = 0.f;
            #pragma unroll
            for (int j = 0; j < 19; ++j) se += __expf(r[j].x - m) + __expf(r[j].y - m);
            if (t0 + lane < il) cl += m + __logf(se);
        }
        asm volatile("s_waitcnt lgkmcnt(0)" ::: "memory");
        __builtin_amdgcn_sched_barrier(0);
        float e[8];
        #pragma unroll
        for (int k = 0; k < 8; ++k) e[k] = buf0[k * RPF + ext];
        #pragma unroll
        for (int k = 0; k < 8; ++k) {
            float e2 = e[k] * LOG2E;
            float b1 = dpp_shr1(beta, NEGV);
            float b2 = dpp_shr1(b1, NEGV);
            b2 = skip ? b2 : NEGV;
            float m3 = fmaxf(fmaxf(beta, b1), b2);
            float s3 = exp2f(beta - m3) + exp2f(b1 - m3) + exp2f(b2 - m3);
            float nbv = m3 + __log2f(s3) + e2;
            beta = (t0 + k < il) ? nbv : beta;
        }
    }

    // ---- KL tail: preload rows/ms (input is L3-resident), then reduce ----
    int posv = 0, tgv = 0;
    if (lane < Sc) {
        posv = pos[b * Sc + lane];
        tgv  = target[b * Sc + lane];
    }
    float xs[Sc], msv[Sc];
    #pragma unroll
    for (int s = 0; s < Sc; ++s) {
        int ps = __shfl(posv, s);
        int tg = __shfl(tgv, s);
        int f  = (s > 0) ? __shfl(tgv, s - 1) : (Cc - 1);
        bool live = (s < tl);
        xs[s]  = (live && lane < Cc) ? row[(size_t)ps * Cc + lane] : 0.0f;
        msv[s] = (live && lane >= 1 && lane < Cc)
                   ? ms[((size_t)(f - 1) * 37 + (tg - 1)) * 37 + (lane - 1)] : 0.0f;
    }
    float klacc = 0.0f;
    #pragma unroll
    for (int s = 0; s < Sc; ++s) {
        if (s < tl) {
            float x = (lane < Cc) ? xs[s] : -1e30f;
            float m = x;
            #pragma unroll
            for (int o = 32; o; o >>= 1) m = fmaxf(m, __shfl_xor(m, o));
            float se = (lane < Cc) ? __expf(x - m) : 0.0f;
            #pragma unroll
            for (int o = 32; o; o >>= 1) se += __shfl_xor(se, o);
            float lsr = m + __logf(se);
            float tv = (lane == 0) ? 1e-10f : ((lane < Cc) ? msv[s] + 1e-10f : 0.0f);
            float term = (lane < Cc) ? tv * (__logf(tv) - (x - lsr)) : 0.0f;
            #pragma unroll
            for (int o = 32; o; o >>= 1) term += __shfl_xor(term, o);
            klacc += term;
        }
    }

    // ---- epilogue ----
    #pragma unroll
    for (int o = 32; o; o >>= 1) cl += __shfl_xor(cl, o);

    const int idx = 2 * tl;                 // 10..60
    float last  = __shfl(beta, idx);
    float last2 = __shfl(beta, idx - 1);
    float mx = fmaxf(last, last2);
    float l2 = (mx + __log2f(exp2f(last - mx) + exp2f(last2 - mx))) * LN2;
    float nll = cl - l2;
    if (nll > 1e8f) nll = 0.0f;             // zero_infinity
    float Lf = (float)tl;
    float ctc_part = nll / (Lf * (float)Bc);
    float smoothing = 1.0f - __expf(-0.05129329438755058f / Lf);  // 1 - 0.95^(1/Lf)
    float kld = klacc * smoothing / ((float)Cc * Lf);

    if (lane == 0) contrib[b] = ctc_part + kld;
}

// Deterministic single-block tree reduction of B floats -> out[0]
__global__ __launch_bounds__(256) void reduce_kernel(
    const float* __restrict__ in, float* __restrict__ out, int n)
{
    __shared__ float sdata[256];
    float s = 0.0f;
    for (int i = threadIdx.x; i < n; i += 256) s += in[i];
    sdata[threadIdx.x] = s;
    __syncthreads();
    for (int off = 128; off; off >>= 1) {
        if ((int)threadIdx.x < off) sdata[threadIdx.x] += sdata[threadIdx.x + off];
        __syncthreads();
    }
    if (threadIdx.x == 0) out[0] = sdata[0];
}

extern "C" void kernel_launch(void* const* d_in, const int* in_sizes, int n_in,
                              void* d_out, int out_size, void* d_ws, size_t ws_size,
                              hipStream_t stream) {
    const float* input  = (const float*)d_in[0];
    const int*   target = (const int*)d_in[1];
    const int*   ilen   = (const int*)d_in[2];
    const int*   tlen   = (const int*)d_in[3];
    const int*   pos    = (const int*)d_in[4];
    const float* ms     = (const float*)d_in[5];
    float* out = (float*)d_out;
    float* contrib = (float*)d_ws;  // B floats

    ctc_fused_kernel<<<Bc / 4, 256, 0, stream>>>(input, target, ilen, tlen, pos, ms, contrib);
    reduce_kernel<<<1, 256, 0, stream>>>(contrib, out, Bc);
}

// Round 9
// 89.042 us; speedup vs baseline: 1.2698x; 1.2440x over previous
//
#include <hip/hip_runtime.h>
#include <math.h>

// Problem constants (fixed by the reference)
constexpr int Bc = 4096;
constexpr int Tc = 200;
constexpr int Cc = 38;   // classes (0 = blank)
constexpr int Sc = 30;   // max target length
constexpr int Lc = 2 * Sc + 1;  // 61 lattice states
#define NEGV (-1e9f)
#define LOG2E 1.4426950408889634f
#define LN2   0.6931471805599453f

// DPP wave_shr:1 — lane i gets v from lane i-1, lane 0 keeps `fill`.
__device__ __forceinline__ float dpp_shr1(float v, float fill) {
    int r = __builtin_amdgcn_update_dpp(__float_as_int(fill), __float_as_int(v),
                                        0x138, 0xF, 0xF, false);
    return __int_as_float(r);
}

// ---------- Pass 1: per-row logsumexp over classes (fully parallel) ----------
__global__ __launch_bounds__(256) void lse_kernel(
    const float* __restrict__ input,  // [B,T,C]
    float*       __restrict__ lse)    // [B*T]
{
    int r = blockIdx.x * 256 + threadIdx.x;
    if (r >= Bc * Tc) return;
    const float2* p = (const float2*)(input + (size_t)r * Cc);
    float x[Cc];
    #pragma unroll
    for (int i = 0; i < Cc / 2; ++i) {
        float2 v = p[i];
        x[2 * i] = v.x; x[2 * i + 1] = v.y;
    }
    float m = x[0];
    #pragma unroll
    for (int i = 1; i < Cc; ++i) m = fmaxf(m, x[i]);
    float s = 0.0f;
    #pragma unroll
    for (int i = 0; i < Cc; ++i) s += __expf(x[i] - m);
    lse[r] = m + __logf(s);
}

// ---------- Pass 2: aligned-KL smoothing, one thread per (b,s) ----------
__global__ __launch_bounds__(256) void kl_kernel(
    const float* __restrict__ input,   // [B,T,C]
    const int*   __restrict__ target,  // [B,S]
    const int*   __restrict__ tlen,    // [B]
    const int*   __restrict__ pos,     // [B,S]
    const float* __restrict__ ms,      // [37,37,37]
    const float* __restrict__ lse_arr, // [B*T]
    float*       __restrict__ klws)    // [B*S] scaled per-(b,s) KL terms
{
    int idx = blockIdx.x * 256 + threadIdx.x;
    if (idx >= Bc * Sc) return;
    int b = idx / Sc;
    int s = idx - b * Sc;
    int tl = tlen[b];
    float outv = 0.0f;
    if (s < tl) {
        int p  = pos[b * Sc + s];
        int tg = target[b * Sc + s];
        int f  = (s > 0) ? target[b * Sc + s - 1] : Cc - 1;
        float lsp = lse_arr[(size_t)b * Tc + p];
        const float* xr  = input + ((size_t)b * Tc + p) * Cc;
        const float* msr = ms + ((size_t)(f - 1) * 37 + (tg - 1)) * 37;
        // c = 0 (blank): sls = 0
        float acc = 1e-10f * (__logf(1e-10f) - (xr[0] - lsp));
        #pragma unroll
        for (int c = 1; c < Cc; ++c) {
            float tv = msr[c - 1] + 1e-10f;
            acc += tv * (__logf(tv) - (xr[c] - lsp));
        }
        float Lf = (float)tl;
        float smoothing = 1.0f - __expf(-0.05129329438755058f / Lf); // 1-0.95^(1/Lf)
        outv = acc * smoothing / ((float)Cc * Lf);
    }
    klws[idx] = outv;
}

// ---------- Pass 3: CTC recursion (log2 shifted space, deep prefetch) ----------
// One wave per sample; lane l = lattice state l.
__global__ __launch_bounds__(256) void ctc_kernel(
    const float* __restrict__ input,    // [B,T,C]
    const int*   __restrict__ target,   // [B,S]
    const int*   __restrict__ ilen,     // [B]
    const int*   __restrict__ tlen,     // [B]
    const float* __restrict__ lse_arr,  // [B*T]
    const float* __restrict__ klws,     // [B*S]
    float*       __restrict__ contrib)  // [B]
{
    const int lane = threadIdx.x & 63;
    const int wave = threadIdx.x >> 6;
    const int b = blockIdx.x * 4 + wave;
    if (b >= Bc) return;

    int ext = 0;
    bool skip = false;
    if (lane < Lc && (lane & 1)) {
        int s = (lane - 1) >> 1;
        ext = target[b * Sc + s];
        int prev = (s > 0) ? target[b * Sc + s - 1] : 0;
        skip = (ext != prev);
    }

    const float* row = input + (size_t)b * Tc * Cc;
    const float* ep  = row + ext;
    const int il = ilen[b];
    const int tl = tlen[b];

    // Rolling register prefetch: PF rows ahead (statically indexed).
    // PF=32: 32 outstanding loads -> ~1120 cy of latency coverage (> ~900 HBM/L3).
    constexpr int PF = 32;
    float pre[PF];
    #pragma unroll
    for (int k = 0; k < PF; ++k) pre[k] = ep[k * Cc];   // k < Tc always

    // beta in LOG2 units; common lse shift cancels (subtracted at the end).
    float beta = (lane == 0) ? 0.0f : NEGV;
    int t = 0;
    for (; t + PF <= il; t += PF) {
        #pragma unroll
        for (int k = 0; k < PF; ++k) {
            float e2 = pre[k] * LOG2E;                  // off critical path
            int tt = t + PF + k;
            tt = (tt < Tc) ? tt : (Tc - 1);             // clamp (OOB guard only)
            pre[k] = ep[tt * Cc];                       // refill PF ahead
            float b1 = dpp_shr1(beta, NEGV);
            float b2 = dpp_shr1(b1, NEGV);
            b2 = skip ? b2 : NEGV;
            float m3 = fmaxf(fmaxf(beta, b1), b2);      // v_max3
            float s3 = exp2f(beta - m3) + exp2f(b1 - m3) + exp2f(b2 - m3);
            beta = m3 + __log2f(s3) + e2;
        }
    }
    // tail (< PF iterations), pre[k] holds values for t..t+PF-1
    #pragma unroll
    for (int k = 0; k < PF; ++k) {
        if (t + k < il) {
            float e2 = pre[k] * LOG2E;
            float b1 = dpp_shr1(beta, NEGV);
            float b2 = dpp_shr1(b1, NEGV);
            b2 = skip ? b2 : NEGV;
            float m3 = fmaxf(fmaxf(beta, b1), b2);
            float s3 = exp2f(beta - m3) + exp2f(b1 - m3) + exp2f(b2 - m3);
            beta = m3 + __log2f(s3) + e2;
        }
    }

    // sum of lse over t < il  +  per-sample KL terms (both lane-parallel)
    const float* lrow = lse_arr + (size_t)b * Tc;
    float cl = 0.0f;
    for (int i = lane; i < il; i += 64) cl += lrow[i];
    float kv = (lane < Sc) ? klws[b * Sc + lane] : 0.0f;
    #pragma unroll
    for (int o = 32; o; o >>= 1) {
        cl += __shfl_xor(cl, o);
        kv += __shfl_xor(kv, o);
    }

    const int idx = 2 * tl;
    float last  = __shfl(beta, idx);
    float last2 = __shfl(beta, idx - 1);
    float mx = fmaxf(last, last2);
    float l2 = (mx + __log2f(exp2f(last - mx) + exp2f(last2 - mx))) * LN2;
    float nll = cl - l2;
    if (nll > 1e8f) nll = 0.0f;             // zero_infinity
    float ctc_part = nll / ((float)tl * (float)Bc);

    if (lane == 0) contrib[b] = ctc_part + kv;
}

// Deterministic single-block tree reduction of B floats -> out[0]
__global__ __launch_bounds__(256) void reduce_kernel(
    const float* __restrict__ in, float* __restrict__ out, int n)
{
    __shared__ float sdata[256];
    float s = 0.0f;
    for (int i = threadIdx.x; i < n; i += 256) s += in[i];
    sdata[threadIdx.x] = s;
    __syncthreads();
    for (int off = 128; off; off >>= 1) {
        if ((int)threadIdx.x < off) sdata[threadIdx.x] += sdata[threadIdx.x + off];
        __syncthreads();
    }
    if (threadIdx.x == 0) out[0] = sdata[0];
}

extern "C" void kernel_launch(void* const* d_in, const int* in_sizes, int n_in,
                              void* d_out, int out_size, void* d_ws, size_t ws_size,
                              hipStream_t stream) {
    const float* input  = (const float*)d_in[0];
    const int*   target = (const int*)d_in[1];
    const int*   ilen   = (const int*)d_in[2];
    const int*   tlen   = (const int*)d_in[3];
    const int*   pos    = (const int*)d_in[4];
    const float* ms     = (const float*)d_in[5];
    float* out = (float*)d_out;

    // ws layout: contrib [Bc] | lse [Bc*Tc] | klws [Bc*Sc]  (~3.9 MB)
    float* contrib = (float*)d_ws;
    float* lse     = contrib + Bc;
    float* klws    = lse + (size_t)Bc * Tc;

    lse_kernel<<<(Bc * Tc + 255) / 256, 256, 0, stream>>>(input, lse);
    kl_kernel<<<(Bc * Sc + 255) / 256, 256, 0, stream>>>(input, target, tlen, pos, ms, lse, klws);
    ctc_kernel<<<Bc / 4, 256, 0, stream>>>(input, target, ilen, tlen, lse, klws, contrib);
    reduce_kernel<<<1, 256, 0, stream>>>(contrib, out, Bc);
}